// Round 7
// baseline (287.810 us; speedup 1.0000x reference)
//
#include <hip/hip_runtime.h>
#include <hip/hip_bf16.h>

// ContrastiveLoss (SimCLR InfoNCE): N=8192, D=1024, T=0.1
// nll[i] = -logit[i, (i+N/2)%N] + logsumexp_j(logit[i,j]), diag masked out
// logit = cos_sim / T; out = mean(nll)
//
// Identities:
//  - zn_i = z_i * sqrt(10*log2e)/||z_i||  =>  dot d = logit*log2e and
//    exp(logit-10) = 2^(d - 10*log2e) -> raw v_exp_f32.
//  - logit in [-10,10] => FIXED-offset logsumexp; masked diagonal term is
//    exactly 0, handled only in the 64 diagonal supertiles.
//  - Gram symmetric: upper-tri 128x128 supertiles (2080 of 4096); off-diag
//    tile (I,J) adds exp row-sums to rows of I, col-sums to rows of J.
//  - positive-pair logits = tile diagonals of supertiles (I, I+32).
//
// R7 (= R6 with the queue bug fixed):
//  - R6 FAILED: per-THREAD atomicAdd on the tile queue gave every thread a
//    different next tile -> intra-block divergence on LDS staging + barriers
//    -> NaN. Replaced with block-uniform static round-robin (t += GRID),
//    which has identical load balance (uniform tile cost) and no atomics.
//  - 64x64 wave tiles, 128x128 supertile, BK=32 dbuf -> LDS 34 KB so 3-4
//    blocks/CU co-reside: cross-block barrier overlap (m114) hides the
//    per-phase vmcnt drain that R4's 2-block residency half-covered.
//  - BK=32 swizzle: stored chunk c holds logical k-chunk c^((r>>1)&3);
//    frag reads hit all 8 bank-groups at 8 lanes each (balanced; R5's
//    (r&3) variant was 4-way imbalanced -> 4.3M conflicts).
//  - Cross-tile prefetch: phase 31 stages the NEXT tile's phase 0, killing
//    the per-tile prologue bubble.

#define N_ROWS 8192
#define DIM    1024
#define BM 128
#define BK 32
#define NPHASE (DIM / BK)              // 32
#define NT     (N_ROWS / BM)           // 64
#define NTILES (NT * (NT + 1) / 2)     // 2080
#define GRID   768
#define OFFS   14.4269504088896340f    // 10 * log2e
#define ROW_SCALE 3.7982825605f        // sqrt(10 * log2e)
#define LN2    0.6931471805599453f
#define LOGIT_MAX 10.0f

typedef __bf16 bf16x8 __attribute__((ext_vector_type(8)));
typedef float floatx4 __attribute__((ext_vector_type(4)));

__device__ __forceinline__ void async_copy16(const __hip_bfloat16* g, void* lds) {
  __builtin_amdgcn_global_load_lds(
      (const __attribute__((address_space(1))) void*)g,
      (__attribute__((address_space(3))) void*)lds, 16, 0, 0);
}

// ---------------- Kernel 1: row normalize (+ zero accumulators) -----------
__global__ __launch_bounds__(256) void normalize_kernel(
    const float* __restrict__ z, __hip_bfloat16* __restrict__ zn,
    float* __restrict__ sumexp, float* __restrict__ out) {
  const int tid = threadIdx.x, wave = tid >> 6, lane = tid & 63;
  const int row = blockIdx.x * 4 + wave;

  if (blockIdx.x < 8) ((float4*)sumexp)[blockIdx.x * 256 + tid] = float4{0, 0, 0, 0};
  if (blockIdx.x == 8 && tid == 0) out[0] = 0.0f;

  const float4* zr = (const float4*)(z + (size_t)row * DIM);
  float4 v[4];
  #pragma unroll
  for (int j = 0; j < 4; j++) v[j] = zr[lane + 64 * j];
  float ss = 0.0f;
  #pragma unroll
  for (int j = 0; j < 4; j++)
    ss += v[j].x * v[j].x + v[j].y * v[j].y + v[j].z * v[j].z + v[j].w * v[j].w;
  #pragma unroll
  for (int off = 32; off > 0; off >>= 1) ss += __shfl_xor(ss, off);
  const float scale = rsqrtf(ss) * ROW_SCALE;  // norms ~32 >> eps

  uint2* o = (uint2*)(zn + (size_t)row * DIM);
  #pragma unroll
  for (int j = 0; j < 4; j++) {
    __hip_bfloat16 ob[4];
    ob[0] = __float2bfloat16(v[j].x * scale);
    ob[1] = __float2bfloat16(v[j].y * scale);
    ob[2] = __float2bfloat16(v[j].z * scale);
    ob[3] = __float2bfloat16(v[j].w * scale);
    o[lane + 64 * j] = *(const uint2*)ob;
  }
}

// decode upper-tri supertile t -> (I, J), I<=J<64; C(I) = I*(129-I)/2
__device__ __forceinline__ void decode_tile(int t, int& I, int& J) {
  int i = (int)(64.5f - sqrtf(64.5f * 64.5f - 2.0f * (float)t));
  while ((i + 1) * (129 - (i + 1)) / 2 <= t) ++i;
  while (i * (129 - i) / 2 > t) --i;
  I = i;
  J = i + (t - i * (129 - i) / 2);
}

// ---------------- Kernel 2: upper-tri GEMM + partial sum-exp --------------
__global__ __launch_bounds__(256) void fused_gemm_lse(
    const __hip_bfloat16* __restrict__ zn, float* __restrict__ sumexp,
    float* __restrict__ pos) {
  __shared__ __hip_bfloat16 sA[2][BM * BK];   // 2 x 8 KB
  __shared__ __hip_bfloat16 sB[2][BM * BK];   // 2 x 8 KB
  __shared__ float rowRed[2][BM];             // 1 KB
  __shared__ float colRed[2][BM];             // 1 KB   (total 34 KB)

  const int tid  = threadIdx.x;
  const int lane = tid & 63;
  const int wave = tid >> 6;
  const int quad = lane >> 4;
  const int l15  = lane & 15;
  const int waveM = wave >> 1;  // 0..1
  const int waveN = wave & 1;   // 0..1

  // staging geometry: 128x32 tile = 512 16B-chunks, 2 per thread per matrix.
  // Stored chunk c=(s&3) holds logical k-chunk q = c ^ ((r>>1)&3)
  int sr[2], sq[2], soff[2];
  #pragma unroll
  for (int i = 0; i < 2; i++) {
    const int sbase = i * 256 + wave * 64;  // wave-uniform chunk base
    const int s = sbase + lane;
    sr[i] = s >> 2;                         // tile row 0..127
    sq[i] = (s & 3) ^ ((sr[i] >> 1) & 3);   // logical k-chunk
    soff[i] = sbase * 16;                   // wave-uniform LDS byte offset
  }

  // frag-read chunk: logical chunk `quad` of row r stored at quad^((r>>1)&3);
  // r = ...16*mi + l15 so (r>>1)&3 = (l15>>1)&3 (per-lane constant)
  const int ca = quad ^ ((l15 >> 1) & 3);

  int t = blockIdx.x;
  int I, J;
  decode_tile(t, I, J);
  int rowBase = I * BM, colBase = J * BM;

  // running staging pointers (advance +BK elems per phase)
  const __hip_bfloat16* aP[2];
  const __hip_bfloat16* bP[2];
  auto setPtrs = [&](int rb, int cb) {
    #pragma unroll
    for (int i = 0; i < 2; i++) {
      aP[i] = zn + (size_t)(rb + sr[i]) * DIM + sq[i] * 8;
      bP[i] = zn + (size_t)(cb + sr[i]) * DIM + sq[i] * 8;
    }
  };
  auto stage = [&](int b) {
    #pragma unroll
    for (int i = 0; i < 2; i++) {
      async_copy16(aP[i], (char*)sA[b] + soff[i]);
      async_copy16(bP[i], (char*)sB[b] + soff[i]);
      aP[i] += BK;
      bP[i] += BK;
    }
  };

  setPtrs(rowBase, colBase);
  stage(0);                       // cur tile phase 0 -> buf 0

  int nT = t + GRID;              // block-uniform next tile (static RR)
  int nI = 0, nJ = 0;
  if (nT < NTILES) decode_tile(nT, nI, nJ);

  floatx4 acc[4][4];
  #pragma unroll
  for (int mi = 0; mi < 4; mi++)
    #pragma unroll
    for (int ni = 0; ni < 4; ni++) acc[mi][ni] = {0.f, 0.f, 0.f, 0.f};

  while (true) {
    for (int p = 0; p < NPHASE; ++p) {
      const int b = p & 1;
      __syncthreads();                 // drains phase p's loads
      if (p < NPHASE - 1) {
        stage(b ^ 1);                  // prefetch next phase of cur tile
      } else if (nT < NTILES) {
        setPtrs(nI * BM, nJ * BM);     // prefetch NEXT TILE's phase 0
        stage(b ^ 1);
      }

      bf16x8 a[4], bb[4];
      #pragma unroll
      for (int mi = 0; mi < 4; mi++)
        a[mi] = ((const bf16x8*)sA[b])[(waveM * 64 + mi * 16 + l15) * 4 + ca];
      #pragma unroll
      for (int ni = 0; ni < 4; ni++)
        bb[ni] = ((const bf16x8*)sB[b])[(waveN * 64 + ni * 16 + l15) * 4 + ca];
      #pragma unroll
      for (int mi = 0; mi < 4; mi++)
        #pragma unroll
        for (int ni = 0; ni < 4; ni++)
          acc[mi][ni] = __builtin_amdgcn_mfma_f32_16x16x32_bf16(
              a[mi], bb[ni], acc[mi][ni], 0, 0, 0);
    }

    // ---- epilogue (overlaps next tile's phase-0 loads) ----
    // C/D layout (16x16): col = lane&15, row = quad*4 + reg  [m89]
    const bool diagBlk = (I == J);

    if (J == I + 32 && waveM == waveN) {  // positive-pair supertile
      #pragma unroll
      for (int mi = 0; mi < 4; mi++)
        #pragma unroll
        for (int r = 0; r < 4; r++)
          if (l15 == quad * 4 + r)
            pos[rowBase + waveM * 64 + mi * 16 + l15] = acc[mi][mi][r];
    }

    float rsum[4][4], csum[4];
    #pragma unroll
    for (int mi = 0; mi < 4; mi++)
      #pragma unroll
      for (int r = 0; r < 4; r++) rsum[mi][r] = 0.0f;
    #pragma unroll
    for (int ni = 0; ni < 4; ni++) csum[ni] = 0.0f;

    if (diagBlk) {
      #pragma unroll
      for (int mi = 0; mi < 4; mi++)
        #pragma unroll
        for (int ni = 0; ni < 4; ni++) {
          const bool dtile = (waveM == waveN) && (mi == ni);
          #pragma unroll
          for (int r = 0; r < 4; r++) {
            float e = exp2f(acc[mi][ni][r] - OFFS);
            if (dtile && l15 == quad * 4 + r) e = 0.0f;  // masked diagonal
            rsum[mi][r] += e;
          }
        }
    } else {
      #pragma unroll
      for (int mi = 0; mi < 4; mi++)
        #pragma unroll
        for (int ni = 0; ni < 4; ni++)
          #pragma unroll
          for (int r = 0; r < 4; r++) {
            const float e = exp2f(acc[mi][ni][r] - OFFS);
            rsum[mi][r] += e;
            csum[ni]    += e;
          }
    }
    #pragma unroll
    for (int mi = 0; mi < 4; mi++)
      #pragma unroll
      for (int ni = 0; ni < 4; ni++) acc[mi][ni] = {0.f, 0.f, 0.f, 0.f};

    #pragma unroll
    for (int mi = 0; mi < 4; mi++)
      #pragma unroll
      for (int r = 0; r < 4; r++) {
        float v = rsum[mi][r];
        v += __shfl_xor(v, 1);
        v += __shfl_xor(v, 2);
        v += __shfl_xor(v, 4);
        v += __shfl_xor(v, 8);
        if (l15 == 0)
          rowRed[waveN][waveM * 64 + mi * 16 + quad * 4 + r] = v;
      }
    if (!diagBlk) {
      #pragma unroll
      for (int ni = 0; ni < 4; ni++) {
        float v = csum[ni];
        v += __shfl_xor(v, 16);
        v += __shfl_xor(v, 32);
        if (quad == 0)
          colRed[waveM][waveN * 64 + ni * 16 + l15] = v;
      }
    }
    __syncthreads();

    if (tid < BM) {
      atomicAdd(&sumexp[rowBase + tid], rowRed[0][tid] + rowRed[1][tid]);
    } else if (!diagBlk) {
      const int c = tid - BM;
      atomicAdd(&sumexp[colBase + c], colRed[0][c] + colRed[1][c]);
    }

    if (nT >= NTILES) break;
    t = nT; I = nI; J = nJ;
    rowBase = I * BM; colBase = J * BM;
    nT = t + GRID;
    if (nT < NTILES) decode_tile(nT, nI, nJ);
  }
}

// ---------------- Kernel 3: mean NLL --------------------------------------
__global__ __launch_bounds__(256) void finalize_kernel(
    const float* __restrict__ sumexp, const float* __restrict__ pos,
    float* __restrict__ out) {
  const int tid = threadIdx.x;
  const int row = blockIdx.x * 256 + tid;
  // pos holds d = logit*log2e for rows [0,4096); pos[i+4096] == pos[i]
  float local = -(pos[row & (N_ROWS / 2 - 1)] * LN2) + LOGIT_MAX + logf(sumexp[row]);
  #pragma unroll
  for (int off = 32; off > 0; off >>= 1) local += __shfl_xor(local, off);
  __shared__ float red[4];
  const int wave = tid >> 6, lane = tid & 63;
  if (lane == 0) red[wave] = local;
  __syncthreads();
  if (tid == 0)
    atomicAdd(out, (red[0] + red[1] + red[2] + red[3]) * (1.0f / N_ROWS));
}

extern "C" void kernel_launch(void* const* d_in, const int* in_sizes, int n_in,
                              void* d_out, int out_size, void* d_ws, size_t ws_size,
                              hipStream_t stream) {
  const float* z = (const float*)d_in[0];
  float* out = (float*)d_out;

  char* ws = (char*)d_ws;
  __hip_bfloat16* zn = (__hip_bfloat16*)ws;                  // 16 MB
  float* sumexp = (float*)(ws + (size_t)N_ROWS * DIM * 2);   // 32 KB
  float* pos    = sumexp + N_ROWS;                           // 16 KB

  normalize_kernel<<<N_ROWS / 4, 256, 0, stream>>>(z, zn, sumexp, out);
  fused_gemm_lse<<<GRID, 256, 0, stream>>>(zn, sumexp, pos);
  finalize_kernel<<<N_ROWS / 256, 256, 0, stream>>>(sumexp, pos, out);
}